// Round 12
// baseline (81.514 us; speedup 1.0000x reference)
//
#include <hip/hip_runtime.h>

// FieldWeightedFactorizationMachine forward — round 11: 4 rows/wave, float4.
// B=32768 rows; F=39 fields; D=64 dims; V=1e6 vocab.
// h=lane>>4 selects the quarter-wave's row; l=lane&15 owns dims 4l..4l+3.
// - 39 NT gather instructions load FOUR rows (9.75 vmem/row vs 19.5 in R10).
// - Triangle on float4 (2x v_pk_fma_f32 per op) — same VALU/row as R10.
// - VGPR ~190: launch_bounds(256,2). Occupancy was flat R0-R2, so 2 waves/SIMD
//   is acceptable risk for the last instruction-rate datapoint.

#define FW_B 32768
#define FW_F 39
#define FW_D 64

typedef float f4 __attribute__((ext_vector_type(4)));

__global__ __launch_bounds__(256, 2) void fwfm_kernel(
    const int*   __restrict__ x,      // (B, F)
    const float* __restrict__ emb,    // (V, D)
    const float* __restrict__ bias,   // (V, 1)
    const float* __restrict__ W,      // (F, F)
    const float* __restrict__ w0,     // (1,)
    float*       __restrict__ out)    // (B,)
{
    const int wave = threadIdx.x >> 6;            // 0..3
    const int lane = threadIdx.x & 63;
    const int h    = lane >> 4;                   // row within the quad 0..3
    const int l    = lane & 15;                   // dim-quad: dims 4l..4l+3
    const int wid  = blockIdx.x * 4 + wave;
    const int row  = wid * 4 + h;                 // grid exact: row < B

    // Field indices for this quarter-wave's row, 16 lanes at a time:
    const int ia = x[row * FW_F + l];                      // fields 0..15
    const int ib = x[row * FW_F + 16 + l];                 // fields 16..31
    const int ic = x[row * FW_F + 32 + (l < 7 ? l : 6)];   // fields 32..38

    // Bias contributions (lane l covers fields l, 16+l, and 32+l when l<7).
    float bsum = bias[(unsigned)ia] + bias[(unsigned)ib];
    if (l < 7) bsum += bias[(unsigned)ic];

    // Gather: 39 NT float4 loads serve all FOUR rows; each quarter-wave
    // (16 lanes x 16B) reads one 256B embedding row. bpermute broadcasts.
    f4 v[FW_F];
    const int src = lane & 48;                    // base lane of this quarter
    #pragma unroll
    for (int i = 0; i < 16; ++i) {
        const int si = __shfl(ia, src + i, 64);
        const unsigned off = (unsigned)si * (unsigned)FW_D + 4u * (unsigned)l;
        v[i] = __builtin_nontemporal_load(reinterpret_cast<const f4*>(emb + off));
    }
    #pragma unroll
    for (int i = 16; i < 32; ++i) {
        const int si = __shfl(ib, src + (i - 16), 64);
        const unsigned off = (unsigned)si * (unsigned)FW_D + 4u * (unsigned)l;
        v[i] = __builtin_nontemporal_load(reinterpret_cast<const f4*>(emb + off));
    }
    #pragma unroll
    for (int i = 32; i < FW_F; ++i) {
        const int si = __shfl(ic, src + (i - 32), 64);
        const unsigned off = (unsigned)si * (unsigned)FW_D + 4u * (unsigned)l;
        v[i] = __builtin_nontemporal_load(reinterpret_cast<const f4*>(emb + off));
    }

    // Upper-triangular weighted pairwise products, packed 4 dims/lane.
    f4 acc = {0.0f, 0.0f, 0.0f, 0.0f};
    #pragma unroll
    for (int i = 0; i < FW_F - 1; ++i) {
        f4 s = {0.0f, 0.0f, 0.0f, 0.0f};
        #pragma unroll
        for (int j = i + 1; j < FW_F; ++j) {
            const float wv = W[i * FW_F + j];
            s += wv * v[j];                       // 2x v_pk_fma_f32
        }
        acc += v[i] * s;
    }

    // Per-lane total (4 dims + bias share), reduce over the 16-lane quarter.
    float t = (acc.x + acc.y) + (acc.z + acc.w) + bsum;
    #pragma unroll
    for (int off = 8; off >= 1; off >>= 1)
        t += __shfl_xor(t, off, 64);              // xor<16: stays in quarter

    if (l == 0)
        out[row] = w0[0] + t;
}

extern "C" void kernel_launch(void* const* d_in, const int* in_sizes, int n_in,
                              void* d_out, int out_size, void* d_ws, size_t ws_size,
                              hipStream_t stream) {
    const int*   x    = (const int*)  d_in[0];
    const float* emb  = (const float*)d_in[1];
    const float* bias = (const float*)d_in[2];
    const float* W    = (const float*)d_in[3];
    const float* w0   = (const float*)d_in[4];
    float* out        = (float*)d_out;

    const int rows_per_block = 4 * 4;              // 4 waves x 4 rows
    const int grid = FW_B / rows_per_block;        // 2048, exact
    fwfm_kernel<<<grid, 256, 0, stream>>>(x, emb, bias, W, w0, out);
}

// Round 13
// 71.623 us; speedup vs baseline: 1.1381x; 1.1381x over previous
//
#include <hip/hip_runtime.h>

// FieldWeightedFactorizationMachine forward — FINAL (round-10 best, 71.5us).
// B=32768 rows; F=39 fields; D=64 dims; V=1e6 vocab.
// h=lane>>5 selects the half-wave's row; l=lane&31 owns dims {2l,2l+1} (float2).
// - 39 NT gather instructions load TWO rows (19.5 vmem/row — swept optimum:
//   39/row=73.7us, 19.5/row=71.5us, 9.75/row=81.5us(reg pressure)).
// - nt policy on the 327MB random embedding stream (best of all 4 cache
//   quadrants; MALL dedup (sc0 sc1) confirmed real but its service path is
//   slower than streaming HBM: 106us @ 208MB fetch).
// - Interaction triangle on float2 -> v_pk_fma_f32.
// Delivered 4.6 TB/s on random 256B gathers = 73% of streaming ceiling.

#define FW_B 32768
#define FW_F 39
#define FW_D 64

typedef float f2 __attribute__((ext_vector_type(2)));

__global__ __launch_bounds__(256, 4) void fwfm_kernel(
    const int*   __restrict__ x,      // (B, F)
    const float* __restrict__ emb,    // (V, D)
    const float* __restrict__ bias,   // (V, 1)
    const float* __restrict__ W,      // (F, F)
    const float* __restrict__ w0,     // (1,)
    float*       __restrict__ out)    // (B,)
{
    const int wave = threadIdx.x >> 6;            // 0..3
    const int lane = threadIdx.x & 63;
    const int h    = lane >> 5;                   // which row of the pair
    const int l    = lane & 31;                   // dim-pair: dims 2l, 2l+1
    const int wid  = blockIdx.x * 4 + wave;
    const int row  = wid * 2 + h;                 // grid sized exactly: row < B

    // Fields 0..31 of this half's row (lane l -> field l):
    const int ia = x[row * FW_F + l];
    // Fields 32..38 at lanes l<7 (clamped elsewhere; only lanes 0..6 are used):
    const int ib = x[row * FW_F + 32 + (l < 7 ? l : 6)];

    // Bias sum for this row, spread over the half-wave's lanes.
    float bsum = bias[(unsigned)ia];
    if (l < 7) bsum += bias[(unsigned)ib];

    // Gather: 39 NT float2 loads serve BOTH rows (half-waves use their own idx).
    // __shfl with per-lane source (h-dependent) -> ds_bpermute.
    f2 v[FW_F];
    const int src = lane & 32;                    // base lane of this half
    #pragma unroll
    for (int i = 0; i < 32; ++i) {
        const int si = __shfl(ia, src + i, 64);
        const unsigned off = (unsigned)si * (unsigned)FW_D + 2u * (unsigned)l;
        v[i] = __builtin_nontemporal_load(reinterpret_cast<const f2*>(emb + off));
    }
    #pragma unroll
    for (int i = 32; i < FW_F; ++i) {
        const int si = __shfl(ib, src + (i - 32), 64);
        const unsigned off = (unsigned)si * (unsigned)FW_D + 2u * (unsigned)l;
        v[i] = __builtin_nontemporal_load(reinterpret_cast<const f2*>(emb + off));
    }

    // Upper-triangular weighted pairwise products, packed 2 dims/lane.
    // W reads wave-uniform, compile-time offsets -> scalar loads; splat to f2.
    f2 acc = {0.0f, 0.0f};
    #pragma unroll
    for (int i = 0; i < FW_F - 1; ++i) {
        f2 s = {0.0f, 0.0f};
        #pragma unroll
        for (int j = i + 1; j < FW_F; ++j) {
            const float wv = W[i * FW_F + j];
            s += wv * v[j];                       // v_pk_fma_f32
        }
        acc += v[i] * s;                          // v_pk_fma_f32
    }

    // Per-lane total (2 dims + bias share), then reduce over the 32-lane half.
    float t = acc.x + acc.y + bsum;
    #pragma unroll
    for (int off = 16; off >= 1; off >>= 1)
        t += __shfl_xor(t, off, 64);              // xor<32: stays within half

    if (l == 0)
        out[row] = w0[0] + t;
}

extern "C" void kernel_launch(void* const* d_in, const int* in_sizes, int n_in,
                              void* d_out, int out_size, void* d_ws, size_t ws_size,
                              hipStream_t stream) {
    const int*   x    = (const int*)  d_in[0];
    const float* emb  = (const float*)d_in[1];
    const float* bias = (const float*)d_in[2];
    const float* W    = (const float*)d_in[3];
    const float* w0   = (const float*)d_in[4];
    float* out        = (float*)d_out;

    const int rows_per_block = 4 * 2;              // 4 waves x 2 rows
    const int grid = FW_B / rows_per_block;        // 4096, exact
    fwfm_kernel<<<grid, 256, 0, stream>>>(x, emb, bias, W, w0, out);
}